// Round 12
// baseline (278.841 us; speedup 1.0000x reference)
//
#include <hip/hip_runtime.h>
#include <hip/hip_bf16.h>
#include <math.h>

typedef short bf16x8 __attribute__((ext_vector_type(8)));
typedef float f32x4 __attribute__((ext_vector_type(4)));

#define DEG_CAP 128   // per-node LDS logit cache; fallback path beyond
#define EPB 8192      // edges per fat partition block

// ---- bf16 helpers (RN-even down-convert, exact up-convert) ----
__device__ __forceinline__ unsigned short f2bf(float f) {
    unsigned x = __float_as_uint(f);
    unsigned r = x + 0x7FFFu + ((x >> 16) & 1u);
    return (unsigned short)(r >> 16);
}
__device__ __forceinline__ float bf2f(unsigned short u) {
    return __uint_as_float(((unsigned)u) << 16);
}
__device__ __forceinline__ f32x4 fma4(float a, f32x4 x, f32x4 c) {
    c[0] = fmaf(a, x[0], c[0]);
    c[1] = fmaf(a, x[1], c[1]);
    c[2] = fmaf(a, x[2], c[2]);
    c[3] = fmaf(a, x[3], c[3]);
    return c;
}

// ===================== prep: bucket-count + conv_x + Wt + Qpk ==================
__global__ __launch_bounds__(256) void prep(const float* __restrict__ x,
                                            unsigned short* __restrict__ X16, int nx4,
                                            const int* __restrict__ dst, int E, int Etot,
                                            int* __restrict__ bcnt,
                                            int* __restrict__ pbh,
                                            const float* __restrict__ W1,
                                            unsigned short* __restrict__ Wt1,
                                            const float* __restrict__ W2,
                                            unsigned short* __restrict__ Wt2,
                                            const float* __restrict__ as1,
                                            const float* __restrict__ ad1,
                                            unsigned short* __restrict__ Q1pkhi,
                                            unsigned short* __restrict__ Q1pklo,
                                            const float* __restrict__ as2,
                                            const float* __restrict__ ad2,
                                            unsigned short* __restrict__ Q2pkhi,
                                            unsigned short* __restrict__ Q2pklo,
                                            int nb_bucket, int nb_convx) {
    int b = blockIdx.x, t = threadIdx.x;
    if (b < nb_bucket) {                      // ---- bucket histogram (dst>>8) ----
        __shared__ int h[256];
        h[t] = 0;
        __syncthreads();
        int k0 = b * EPB;
        for (int i = t; i < EPB; i += 256) {
            int k = k0 + i;
            if (k < Etot) {
                int d = k < E ? dst[k] : k - E;
                atomicAdd(&h[d >> 8], 1);
            }
        }
        __syncthreads();
        pbh[b * 256 + t] = h[t];
        if (h[t]) atomicAdd(bcnt + t, h[t]);
        return;
    }
    b -= nb_bucket;
    if (b < nb_convx) {                       // ---- x fp32 -> bf16 (float4) ----
        int i = b * 256 + t;
        if (i < nx4) {
            float4 v = ((const float4*)x)[i];
            ushort4 u;
            u.x = f2bf(v.x); u.y = f2bf(v.y); u.z = f2bf(v.z); u.w = f2bf(v.w);
            ((ushort4*)X16)[i] = u;
        }
        return;
    }
    b -= nb_convx;
    if (b < 128) {                            // ---- W1 [128][256] -> Wt1 [256][128]
        int id = b * 256 + t;
        int k = id >> 8, m = id & 255;
        Wt1[m * 128 + k] = f2bf(W1[id]);
        return;
    }
    b -= 128;
    if (b < 128) {                            // ---- W2 [256][128] -> Wt2 [128][256]
        int id = b * 256 + t;
        int k = id >> 7, m = id & 127;
        Wt2[m * 256 + k] = f2bf(W2[id]);
        return;
    }
    b -= 128;
    int wave = t >> 6, lane = t & 63;
    if (b < 32) {                             // ---- Q1 [128 k][8] -> pk panels ----
        int k = b * 4 + wave;
        if (k < 128) {
            float p[8];
            #pragma unroll
            for (int h = 0; h < 4; ++h) {
                float w = W1[k * 256 + h * 64 + lane];
                p[h] = w * as1[h * 64 + lane];
                p[4 + h] = w * ad1[h * 64 + lane];
            }
            #pragma unroll
            for (int j = 0; j < 8; ++j)
                #pragma unroll
                for (int o = 32; o; o >>= 1) p[j] += __shfl_xor(p[j], o);
            if (lane == 0) {
                #pragma unroll
                for (int j = 0; j < 8; ++j) {
                    unsigned short hi = f2bf(p[j]);
                    Q1pkhi[j * 128 + k] = hi;
                    Q1pklo[j * 128 + k] = f2bf(p[j] - bf2f(hi));
                }
            }
        }
        return;
    }
    b -= 32;
    {                                         // ---- Q2 [256 k][2] -> pk panels ----
        int k = b * 4 + wave;
        if (k < 256) {
            float w0 = W2[k * 128 + lane], w1 = W2[k * 128 + 64 + lane];
            float s = w0 * as2[lane] + w1 * as2[64 + lane];
            float d = w0 * ad2[lane] + w1 * ad2[64 + lane];
            #pragma unroll
            for (int o = 32; o; o >>= 1) { s += __shfl_xor(s, o); d += __shfl_xor(d, o); }
            if (lane == 0) {
                unsigned short sh = f2bf(s), dh = f2bf(d);
                Q2pkhi[k] = sh;
                Q2pkhi[256 + k] = dh;
                Q2pklo[k] = f2bf(s - bf2f(sh));
                Q2pklo[256 + k] = f2bf(d - bf2f(dh));
            }
        }
    }
}

// ===================== fused: partition + attn1 (X.Q1 via MFMA) ==============
__global__ __launch_bounds__(256) void part_attn1(const unsigned short* __restrict__ Xb,
                                                  const unsigned short* __restrict__ Q1pkhi,
                                                  const unsigned short* __restrict__ Q1pklo,
                                                  float* __restrict__ es,
                                                  float* __restrict__ ed,
                                                  int N, int PB,
                                                  const int* __restrict__ src,
                                                  const int* __restrict__ dst,
                                                  int E, int Etot,
                                                  const int* __restrict__ bcnt,
                                                  const int* __restrict__ pbh,
                                                  int* __restrict__ bcursor,
                                                  int* __restrict__ ebuf) {
    int t = threadIdx.x;
    if ((int)blockIdx.x < PB) {
        __shared__ int gb[256], lc[256], sc[256];
        int v0 = bcnt[t];
        sc[t] = v0;
        __syncthreads();
        #pragma unroll
        for (int o = 1; o < 256; o <<= 1) {
            int add = t >= o ? sc[t - o] : 0;
            __syncthreads();
            sc[t] += add;
            __syncthreads();
        }
        int mybase = sc[t] - v0;              // exclusive bucket base
        int hv = pbh[(int)blockIdx.x * 256 + t];
        if (hv) gb[t] = mybase + atomicAdd(bcursor + t, hv);
        lc[t] = 0;
        __syncthreads();
        int k0 = (int)blockIdx.x * EPB;
        for (int i = t; i < EPB; i += 256) {
            int k = k0 + i;
            if (k < Etot) {
                int s = k < E ? src[k] : k - E;
                int d = k < E ? dst[k] : k - E;
                int bkt = d >> 8;
                int p = atomicAdd(&lc[bkt], 1);
                ebuf[gb[bkt] + p] = s | ((d & 0xFF) << 16);  // src:16|dlow:8
            }
        }
        return;
    }
    int wave = t >> 6, lane = t & 63;
    int l15 = lane & 15, quad = lane >> 4;
    int n0 = ((int)blockIdx.x - PB) * 64 + wave * 16;
    if (n0 >= N) return;
    int ar = n0 + l15; if (ar >= N) ar = N - 1;
    const unsigned short* arow = Xb + (size_t)ar * 128 + quad * 8;
    const unsigned short* bh = Q1pkhi + l15 * 128 + quad * 8;
    const unsigned short* bl = Q1pklo + l15 * 128 + quad * 8;
    f32x4 acc = {};
    #pragma unroll
    for (int k0 = 0; k0 < 128; k0 += 32) {
        bf16x8 a = *(const bf16x8*)(arow + k0);
        acc = __builtin_amdgcn_mfma_f32_16x16x32_bf16(
            a, *(const bf16x8*)(bh + k0), acc, 0, 0, 0);
        acc = __builtin_amdgcn_mfma_f32_16x16x32_bf16(
            a, *(const bf16x8*)(bl + k0), acc, 0, 0, 0);
    }
    #pragma unroll
    for (int r = 0; r < 4; ++r) {
        int n = n0 + quad * 4 + r;
        if (n < N) {
            if (l15 < 4)      es[n * 4 + l15] = acc[r];
            else if (l15 < 8) ed[n * 4 + (l15 - 4)] = acc[r];
        }
    }
}

// ===================== per-bucket CSR build (XCD-local writes) =================
__global__ __launch_bounds__(256) void bucket_scatter(const int* __restrict__ bcnt,
                                                      const int* __restrict__ ebuf,
                                                      int* __restrict__ rowptr,
                                                      int* __restrict__ col,
                                                      int N, int Etot) {
    __shared__ int sb[256], ldeg[256], loff[256], lcur[256];
    int b = blockIdx.x, t = threadIdx.x;
    sb[t] = bcnt[t];
    ldeg[t] = 0;
    __syncthreads();
    #pragma unroll
    for (int o = 1; o < 256; o <<= 1) {
        int add = t >= o ? sb[t - o] : 0;
        __syncthreads();
        sb[t] += add;
        __syncthreads();
    }
    int cnt = bcnt[b];
    int base = sb[b] - cnt;                   // exclusive bucket base
    if (b == 0 && t == 0) rowptr[N] = Etot;
    for (int i = t; i < cnt; i += 256) {
        int e = ebuf[base + i];
        atomicAdd(&ldeg[(e >> 16) & 0xFF], 1);
    }
    __syncthreads();
    int v = ldeg[t];
    loff[t] = v;
    __syncthreads();
    #pragma unroll
    for (int o = 1; o < 256; o <<= 1) {
        int add = t >= o ? loff[t - o] : 0;
        __syncthreads();
        loff[t] += add;
        __syncthreads();
    }
    int excl = loff[t] - v;
    __syncthreads();
    loff[t] = excl;
    lcur[t] = 0;
    int node = b * 256 + t;
    if (node < N) rowptr[node] = base + excl;
    __syncthreads();
    for (int i = t; i < cnt; i += 256) {
        int e = ebuf[base + i];
        int dl = (e >> 16) & 0xFF;
        int p = atomicAdd(&lcur[dl], 1);
        col[base + loff[dl] + p] = e & 0xFFFF;
    }
}

// ===================== agg_proj: fused agg_l1 + proj + attn2 (16 waves) =======
// Block = 1024 threads = 16 waves = 16 nodes, ONE NODE PER WAVE (R10's 4-node
// serial loop collapsed gather TLP; this keeps agg_l1x's exact parallelism:
// 2 blocks/CU = 2048 threads). Phase G = byte-identical R4 gather algorithm,
// output to Glds instead of G16 (kills 50 MB write + 50 MB re-read + launch).
// Phase A: wave w -> (head w>>2, col-tile w&3), one 16x16 MFMA tile -> Hlds.
// Phase B1: waves 0-7 one 16-col slab each (K=256). Phase B2: wave 8, attn2.
// LDS: gather scratch (41 KB) + Glds (16.6 KB) = 57.6 KB -> 2 blocks/CU;
// Hlds overlays the dead gather scratch.
__global__ __launch_bounds__(1024, 8) void agg_proj(const int* __restrict__ rowptr,
                                                    const int* __restrict__ col,
                                                    const unsigned short* __restrict__ x16,
                                                    const float* __restrict__ es,
                                                    const float* __restrict__ ed,
                                                    const unsigned short* __restrict__ Wt1,
                                                    const float* __restrict__ b1,
                                                    const unsigned short* __restrict__ Wt2,
                                                    const unsigned short* __restrict__ Q2pkhi,
                                                    const unsigned short* __restrict__ Q2pklo,
                                                    unsigned short* __restrict__ H2,
                                                    float* __restrict__ es2,
                                                    float* __restrict__ ed2, int N) {
    __shared__ __align__(16) char ubuf[41216];          // overlay region
    float (*pl)[DEG_CAP * 4] = (float(*)[DEG_CAP * 4])ubuf;          // [16][512] f32
    int (*ic)[DEG_CAP] = (int(*)[DEG_CAP])(ubuf + 32768);            // [16][128] i32
    float (*zs)[4] = (float(*)[4])(ubuf + 40960);                    // [16][4]  f32
    unsigned short (*Hlds)[264] = (unsigned short(*)[264])ubuf;      // [16][264]
    __shared__ unsigned short Glds[16][520];            // 16 rows x 512 (+8 pad)
    int wave = threadIdx.x >> 6, lane = threadIdx.x & 63;
    int h = lane >> 4, l16 = lane & 15;
    int half = lane >> 5, l32 = lane & 31;
    int l15 = lane & 15, quad = lane >> 4;
    int m0 = blockIdx.x * 16;
    int n = m0 + wave;
    // ---- phase G: gather-aggregate, ONE node per wave (R4-proven body) ----
    {
        const unsigned short* xb = x16 + l32 * 4;
        float* myp = pl[wave];
        int* myc = ic[wave];
        f32x4 acc[4] = {};
        bool live = n < N;
        int beg = 0, end = 0, deg = 0;
        if (live) { beg = rowptr[n]; end = rowptr[n + 1]; deg = end - beg; }
        if (live && deg <= DEG_CAP) {
            float edv = ed[n * 4 + h];
            float z = 0.f;
            for (int i = l16; i < deg; i += 16) {
                int s = col[beg + i];
                if (h == 0) myc[i] = s;
                float e = es[s * 4 + h] + edv;
                e = e > 0.f ? e : 0.2f * e;
                float pp = __expf(e);
                myp[i * 4 + h] = pp;
                z += pp;
            }
            #pragma unroll
            for (int o = 8; o; o >>= 1) z += __shfl_xor(z, o);
            if (l16 == 0) zs[wave][h] = 1.0f / z;
            __threadfence_block();
            float4 zi = *(float4*)zs[wave];
            int i = 0;
            for (; i + 4 <= deg; i += 4) {
                int iA = i + half, iB = iA + 2;
                int sA = myc[iA], sB = myc[iB];
                float4 pA = *(float4*)(myp + iA * 4);
                float4 pB = *(float4*)(myp + iB * 4);
                ushort4 uA = *(const ushort4*)(xb + (size_t)sA * 128);
                ushort4 uB = *(const ushort4*)(xb + (size_t)sB * 128);
                f32x4 xA = {bf2f(uA.x), bf2f(uA.y), bf2f(uA.z), bf2f(uA.w)};
                acc[0] = fma4(pA.x * zi.x, xA, acc[0]);
                acc[1] = fma4(pA.y * zi.y, xA, acc[1]);
                acc[2] = fma4(pA.z * zi.z, xA, acc[2]);
                acc[3] = fma4(pA.w * zi.w, xA, acc[3]);
                f32x4 xB = {bf2f(uB.x), bf2f(uB.y), bf2f(uB.z), bf2f(uB.w)};
                acc[0] = fma4(pB.x * zi.x, xB, acc[0]);
                acc[1] = fma4(pB.y * zi.y, xB, acc[1]);
                acc[2] = fma4(pB.z * zi.z, xB, acc[2]);
                acc[3] = fma4(pB.w * zi.w, xB, acc[3]);
            }
            for (; i < deg; i += 2) {
                int ii = i + half;
                if (ii < deg) {
                    int s = myc[ii];
                    float4 p = *(float4*)(myp + ii * 4);
                    ushort4 u = *(const ushort4*)(xb + (size_t)s * 128);
                    f32x4 xv = {bf2f(u.x), bf2f(u.y), bf2f(u.z), bf2f(u.w)};
                    acc[0] = fma4(p.x * zi.x, xv, acc[0]);
                    acc[1] = fma4(p.y * zi.y, xv, acc[1]);
                    acc[2] = fma4(p.z * zi.z, xv, acc[2]);
                    acc[3] = fma4(p.w * zi.w, xv, acc[3]);
                }
            }
        } else if (live) {
            // fallback: recompute logits per edge (deg > DEG_CAP, rare)
            float edv = ed[n * 4 + h];
            float z2 = 0.f;
            for (int e = beg + l16; e < end; e += 16) {
                float ev = es[col[e] * 4 + h] + edv;
                ev = ev > 0.f ? ev : 0.2f * ev;
                z2 += __expf(ev);
            }
            #pragma unroll
            for (int o = 8; o; o >>= 1) z2 += __shfl_xor(z2, o);
            if (l16 == 0) zs[wave][h] = 1.0f / z2;
            __threadfence_block();
            float4 zi = *(float4*)zs[wave];
            float4 ed4 = *(const float4*)(ed + (size_t)n * 4);
            for (int e = beg; e < end; e += 2) {
                int ee = e + half;
                if (ee < end) {
                    int s = col[ee];
                    float4 es4 = *(const float4*)(es + (size_t)s * 4);
                    float e0 = es4.x + ed4.x; e0 = e0 > 0.f ? e0 : 0.2f * e0;
                    float e1 = es4.y + ed4.y; e1 = e1 > 0.f ? e1 : 0.2f * e1;
                    float e2 = es4.z + ed4.z; e2 = e2 > 0.f ? e2 : 0.2f * e2;
                    float e3 = es4.w + ed4.w; e3 = e3 > 0.f ? e3 : 0.2f * e3;
                    ushort4 u = *(const ushort4*)(xb + (size_t)s * 128);
                    f32x4 xv = {bf2f(u.x), bf2f(u.y), bf2f(u.z), bf2f(u.w)};
                    acc[0] = fma4(__expf(e0) * zi.x, xv, acc[0]);
                    acc[1] = fma4(__expf(e1) * zi.y, xv, acc[1]);
                    acc[2] = fma4(__expf(e2) * zi.z, xv, acc[2]);
                    acc[3] = fma4(__expf(e3) * zi.w, xv, acc[3]);
                }
            }
        }
        #pragma unroll
        for (int hh = 0; hh < 4; ++hh)
            #pragma unroll
            for (int c = 0; c < 4; ++c)
                acc[hh][c] += __shfl_xor(acc[hh][c], 32);
        if (half == 0) {
            #pragma unroll
            for (int hh = 0; hh < 4; ++hh) {
                ushort4 o = {f2bf(acc[hh][0]), f2bf(acc[hh][1]),
                             f2bf(acc[hh][2]), f2bf(acc[hh][3])};
                *(ushort4*)(&Glds[wave][hh * 128 + l32 * 4]) = o;
            }
        }
    }
    __syncthreads();   // Glds complete; gather scratch dead -> Hlds reusable
    // ---- phase A: wave w -> head w>>2, col-tile w&3 (16x16, K=128) ----
    {
        int hh = wave >> 2, nt = wave & 3;
        f32x4 acc = {};
        const unsigned short* brow = Wt1 + (size_t)(hh * 64 + nt * 16 + l15) * 128 + quad * 8;
        #pragma unroll
        for (int k0 = 0; k0 < 128; k0 += 32) {
            bf16x8 a = *(const bf16x8*)(&Glds[l15][hh * 128 + quad * 8 + k0]);
            acc = __builtin_amdgcn_mfma_f32_16x16x32_bf16(
                a, *(const bf16x8*)(brow + k0), acc, 0, 0, 0);
        }
        float bias = b1[hh * 64 + nt * 16 + l15];
        #pragma unroll
        for (int r = 0; r < 4; ++r) {
            float v = acc[r] + bias;
            v = v > 0.f ? v : (__expf(v) - 1.0f);
            Hlds[quad * 4 + r][hh * 64 + nt * 16 + l15] = f2bf(v);
        }
    }
    __syncthreads();
    // ---- phase B1: waves 0-7, one 16-col slab each (K=256) ----
    if (wave < 8) {
        f32x4 acc = {};
        const unsigned short* brow = Wt2 + (size_t)(wave * 16 + l15) * 256 + quad * 8;
        #pragma unroll
        for (int k0 = 0; k0 < 256; k0 += 32) {
            bf16x8 a = *(const bf16x8*)(&Hlds[l15][quad * 8 + k0]);
            acc = __builtin_amdgcn_mfma_f32_16x16x32_bf16(
                a, *(const bf16x8*)(brow + k0), acc, 0, 0, 0);
        }
        #pragma unroll
        for (int r = 0; r < 4; ++r) {
            int row = m0 + quad * 4 + r;
            if (row < N)
                H2[(size_t)row * 128 + wave * 16 + l15] = f2bf(acc[r]);
        }
    } else if (wave == 8) {
        // ---- phase B2: attn2 via MFMA (Q2 hi/lo panels) ----
        f32x4 acc = {};
        const unsigned short* bh2 = Q2pkhi + l15 * 256 + quad * 8;
        const unsigned short* bl2 = Q2pklo + l15 * 256 + quad * 8;
        #pragma unroll
        for (int k0 = 0; k0 < 256; k0 += 32) {
            bf16x8 a = *(const bf16x8*)(&Hlds[l15][quad * 8 + k0]);
            acc = __builtin_amdgcn_mfma_f32_16x16x32_bf16(
                a, *(const bf16x8*)(bh2 + k0), acc, 0, 0, 0);
            acc = __builtin_amdgcn_mfma_f32_16x16x32_bf16(
                a, *(const bf16x8*)(bl2 + k0), acc, 0, 0, 0);
        }
        #pragma unroll
        for (int r = 0; r < 4; ++r) {
            int nn = m0 + quad * 4 + r;
            if (nn < N) {
                if (l15 == 0)      es2[nn] = acc[r];
                else if (l15 == 1) ed2[nn] = acc[r];
            }
        }
    }
}

// ===================== agg_l2 (no-max softmax; gather h2 rows 256B) =========
__global__ __launch_bounds__(256) void agg_l2(const int* __restrict__ rowptr,
                                              const int* __restrict__ col,
                                              const unsigned short* __restrict__ h16,
                                              const float* __restrict__ es,
                                              const float* __restrict__ ed,
                                              const float* __restrict__ b2,
                                              float* __restrict__ out, int N) {
    __shared__ float pl[4][DEG_CAP];
    __shared__ int ic[4][DEG_CAP];
    int wave = threadIdx.x >> 6, lane = threadIdx.x & 63;
    int n = blockIdx.x * 4 + wave;
    if (n >= N) return;
    int beg = rowptr[n], end = rowptr[n + 1], deg = end - beg;
    float edv = ed[n];
    float* myp = pl[wave];
    int* myc = ic[wave];
    float z = 0.f, zinv;
    int half = lane >> 5, l32 = lane & 31;
    float4 acc0 = make_float4(0.f, 0.f, 0.f, 0.f);
    float4 acc1 = make_float4(0.f, 0.f, 0.f, 0.f);
    float4 acc2 = make_float4(0.f, 0.f, 0.f, 0.f);
    float4 acc3 = make_float4(0.f, 0.f, 0.f, 0.f);
    if (deg <= DEG_CAP) {
        for (int i = lane; i < deg; i += 64) {
            int s = col[beg + i];
            myc[i] = s;
            float e = es[s] + edv;
            e = e > 0.f ? e : 0.2f * e;
            float pp = __expf(e);
            myp[i] = pp;
            z += pp;
        }
        #pragma unroll
        for (int o = 32; o; o >>= 1) z += __shfl_xor(z, o);
        zinv = 1.0f / z;
        __threadfence_block();
        int i = 0;
        for (; i + 8 <= deg; i += 8) {
            int ii0 = i + half, ii1 = i + 2 + half, ii2 = i + 4 + half, ii3 = i + 6 + half;
            float a0 = myp[ii0] * zinv, a1 = myp[ii1] * zinv;
            float a2 = myp[ii2] * zinv, a3 = myp[ii3] * zinv;
            ushort4 u0 = *(const ushort4*)(h16 + (size_t)myc[ii0] * 128 + l32 * 4);
            ushort4 u1 = *(const ushort4*)(h16 + (size_t)myc[ii1] * 128 + l32 * 4);
            ushort4 u2 = *(const ushort4*)(h16 + (size_t)myc[ii2] * 128 + l32 * 4);
            ushort4 u3 = *(const ushort4*)(h16 + (size_t)myc[ii3] * 128 + l32 * 4);
            acc0.x = fmaf(a0, bf2f(u0.x), acc0.x);
            acc0.y = fmaf(a0, bf2f(u0.y), acc0.y);
            acc0.z = fmaf(a0, bf2f(u0.z), acc0.z);
            acc0.w = fmaf(a0, bf2f(u0.w), acc0.w);
            acc1.x = fmaf(a1, bf2f(u1.x), acc1.x);
            acc1.y = fmaf(a1, bf2f(u1.y), acc1.y);
            acc1.z = fmaf(a1, bf2f(u1.z), acc1.z);
            acc1.w = fmaf(a1, bf2f(u1.w), acc1.w);
            acc2.x = fmaf(a2, bf2f(u2.x), acc2.x);
            acc2.y = fmaf(a2, bf2f(u2.y), acc2.y);
            acc2.z = fmaf(a2, bf2f(u2.z), acc2.z);
            acc2.w = fmaf(a2, bf2f(u2.w), acc2.w);
            acc3.x = fmaf(a3, bf2f(u3.x), acc3.x);
            acc3.y = fmaf(a3, bf2f(u3.y), acc3.y);
            acc3.z = fmaf(a3, bf2f(u3.z), acc3.z);
            acc3.w = fmaf(a3, bf2f(u3.w), acc3.w);
        }
        for (; i < deg; i += 2) {
            int ii = i + half;
            if (ii < deg) {
                float a0 = myp[ii] * zinv;
                ushort4 u0 = *(const ushort4*)(h16 + (size_t)myc[ii] * 128 + l32 * 4);
                acc0.x = fmaf(a0, bf2f(u0.x), acc0.x);
                acc0.y = fmaf(a0, bf2f(u0.y), acc0.y);
                acc0.z = fmaf(a0, bf2f(u0.z), acc0.z);
                acc0.w = fmaf(a0, bf2f(u0.w), acc0.w);
            }
        }
    } else {
        for (int e = beg + lane; e < end; e += 64) {
            float ev = es[col[e]] + edv;
            ev = ev > 0.f ? ev : 0.2f * ev;
            z += __expf(ev);
        }
        #pragma unroll
        for (int o = 32; o; o >>= 1) z += __shfl_xor(z, o);
        zinv = 1.0f / z;
        for (int e = beg; e < end; e += 2) {
            int ee = e + half;
            if (ee < end) {
                int s = col[ee];
                float ev = es[s] + edv;
                ev = ev > 0.f ? ev : 0.2f * ev;
                float alpha = __expf(ev) * zinv;
                ushort4 u = *(const ushort4*)(h16 + (size_t)s * 128 + l32 * 4);
                acc0.x = fmaf(alpha, bf2f(u.x), acc0.x);
                acc0.y = fmaf(alpha, bf2f(u.y), acc0.y);
                acc0.z = fmaf(alpha, bf2f(u.z), acc0.z);
                acc0.w = fmaf(alpha, bf2f(u.w), acc0.w);
            }
        }
    }
    float4 acc = make_float4((acc0.x + acc1.x) + (acc2.x + acc3.x),
                             (acc0.y + acc1.y) + (acc2.y + acc3.y),
                             (acc0.z + acc1.z) + (acc2.z + acc3.z),
                             (acc0.w + acc1.w) + (acc2.w + acc3.w));
    acc.x += __shfl_xor(acc.x, 32);
    acc.y += __shfl_xor(acc.y, 32);
    acc.z += __shfl_xor(acc.z, 32);
    acc.w += __shfl_xor(acc.w, 32);
    if (half == 0) {
        float4 bv = *(const float4*)(b2 + l32 * 4);
        *(float4*)(out + (size_t)n * 128 + l32 * 4) =
            make_float4(acc.x + bv.x, acc.y + bv.y, acc.z + bv.z, acc.w + bv.w);
    }
}

// ===================== launch =====================
extern "C" void kernel_launch(void* const* d_in, const int* in_sizes, int n_in,
                              void* d_out, int out_size, void* d_ws, size_t ws_size,
                              hipStream_t stream) {
    const float* x   = (const float*)d_in[0];
    const int*   ei  = (const int*)d_in[1];
    const float* W1  = (const float*)d_in[2];
    const float* as1 = (const float*)d_in[3];
    const float* ad1 = (const float*)d_in[4];
    const float* b1  = (const float*)d_in[5];
    const float* W2  = (const float*)d_in[6];
    const float* as2 = (const float*)d_in[7];
    const float* ad2 = (const float*)d_in[8];
    const float* b2  = (const float*)d_in[9];
    float* out = (float*)d_out;

    const int N = in_sizes[0] / 128;   // 50000
    const int E = in_sizes[1] / 2;     // 800000
    const int Etot = E + N;
    const int* src = ei;
    const int* dst = ei + E;
    const int NBUCK = (N + 255) / 256;        // 196 buckets of 256 nodes
    const int PB = (Etot + EPB - 1) / EPB;    // fat partition blocks

    // ---- workspace layout (16B-aligned chunks) ----
    char* p = (char*)d_ws;
    unsigned short* X16 = (unsigned short*)p; p += (size_t)N * 128 * 2;
    unsigned short* H2  = (unsigned short*)p; p += (size_t)N * 128 * 2;
    unsigned short* Wt1 = (unsigned short*)p; p += (size_t)256 * 128 * 2;
    unsigned short* Wt2 = (unsigned short*)p; p += (size_t)128 * 256 * 2;
    unsigned short* Q1pkhi = (unsigned short*)p; p += 16 * 128 * 2;
    unsigned short* Q1pklo = (unsigned short*)p; p += 16 * 128 * 2;
    unsigned short* Q2pkhi = (unsigned short*)p; p += 16 * 256 * 2;
    unsigned short* Q2pklo = (unsigned short*)p; p += 16 * 256 * 2;
    float* es1 = (float*)p;               p += (size_t)N * 4 * 4;
    float* ed1 = (float*)p;               p += (size_t)N * 4 * 4;
    float* es2 = (float*)p;               p += (size_t)N * 4;
    float* ed2 = (float*)p;               p += (size_t)N * 4;
    int* bcnt = (int*)p;                  p += 256 * 4;   // memset to 0 (with bcursor)
    int* bcursor = (int*)p;               p += 256 * 4;
    int* pbh = (int*)p;                   p += (size_t)PB * 256 * 4;
    int* ebuf = (int*)p;                  p += (size_t)Etot * 4;
    int* col = (int*)p;                   p += (size_t)Etot * 4;
    int* rowptr = (int*)p;                p += (size_t)(N + 1) * 4;

    // ---- prep (bucket-count first, then conv + Wt + Qpk) ----
    const int nx4 = N * 128 / 4;
    const int nb_convx = (nx4 + 255) / 256;
    const int nb_prep = PB + nb_convx + 128 + 128 + 32 + 64;
    hipMemsetAsync(bcnt, 0, 512 * sizeof(int), stream);   // bcnt + bcursor
    prep<<<nb_prep, 256, 0, stream>>>(x, X16, nx4, dst, E, Etot, bcnt, pbh,
                                      W1, Wt1, W2, Wt2, as1, ad1, Q1pkhi, Q1pklo,
                                      as2, ad2, Q2pkhi, Q2pklo, PB, nb_convx);

    // ---- partition + attn1 (MFMA, 64 nodes/block); scan + pbh reuse ----
    const int AB = (N + 63) / 64;
    part_attn1<<<PB + AB, 256, 0, stream>>>(X16, Q1pkhi, Q1pklo, es1, ed1, N, PB,
                                            src, dst, E, Etot, bcnt, pbh,
                                            bcursor, ebuf);

    // ---- per-bucket CSR build (XCD-local writes); scan folded in ----
    bucket_scatter<<<NBUCK, 256, 0, stream>>>(bcnt, ebuf, rowptr, col, N, Etot);

    // ---- fused layer-1 aggregation + projection + GEMM2 + attn2 ----
    const int tiles = (N + 15) / 16;
    agg_proj<<<tiles, 1024, 0, stream>>>(rowptr, col, X16, es1, ed1,
                                         Wt1, b1, Wt2, Q2pkhi, Q2pklo,
                                         H2, es2, ed2, N);

    // ---- layer 2 aggregation ----
    agg_l2<<<(N + 3) / 4, 256, 0, stream>>>(rowptr, col, H2, es2, ed2, b2, out, N);
}

// Round 13
// 256.259 us; speedup vs baseline: 1.0881x; 1.0881x over previous
//
#include <hip/hip_runtime.h>
#include <hip/hip_bf16.h>
#include <math.h>

typedef short bf16x8 __attribute__((ext_vector_type(8)));
typedef float f32x4 __attribute__((ext_vector_type(4)));

#define DEG_CAP 128   // per-node LDS logit cache; fallback path beyond
#define EPB 8192      // edges per fat partition block

// ---- bf16 helpers (RN-even down-convert, exact up-convert) ----
__device__ __forceinline__ unsigned short f2bf(float f) {
    unsigned x = __float_as_uint(f);
    unsigned r = x + 0x7FFFu + ((x >> 16) & 1u);
    return (unsigned short)(r >> 16);
}
__device__ __forceinline__ float bf2f(unsigned short u) {
    return __uint_as_float(((unsigned)u) << 16);
}
__device__ __forceinline__ f32x4 fma4(float a, f32x4 x, f32x4 c) {
    c[0] = fmaf(a, x[0], c[0]);
    c[1] = fmaf(a, x[1], c[1]);
    c[2] = fmaf(a, x[2], c[2]);
    c[3] = fmaf(a, x[3], c[3]);
    return c;
}

// ===================== prep: bucket-count + conv_x + Wt + Qpk ==================
// Bucket-histogram blocks also persist their per-block 256-bucket counts to
// pbh[block][bucket] so part_attn1's partition phase can skip its re-count
// pass (R8: one full edge-data pass eliminated).
__global__ __launch_bounds__(256) void prep(const float* __restrict__ x,
                                            unsigned short* __restrict__ X16, int nx4,
                                            const int* __restrict__ dst, int E, int Etot,
                                            int* __restrict__ bcnt,
                                            int* __restrict__ pbh,
                                            const float* __restrict__ W1,
                                            unsigned short* __restrict__ Wt1,
                                            const float* __restrict__ W2,
                                            unsigned short* __restrict__ Wt2,
                                            const float* __restrict__ as1,
                                            const float* __restrict__ ad1,
                                            unsigned short* __restrict__ Q1pkhi,
                                            unsigned short* __restrict__ Q1pklo,
                                            const float* __restrict__ as2,
                                            const float* __restrict__ ad2,
                                            unsigned short* __restrict__ Q2pkhi,
                                            unsigned short* __restrict__ Q2pklo,
                                            int nb_bucket, int nb_convx) {
    int b = blockIdx.x, t = threadIdx.x;
    if (b < nb_bucket) {                      // ---- bucket histogram (dst>>8) ----
        __shared__ int h[256];
        h[t] = 0;
        __syncthreads();
        int k0 = b * EPB;
        for (int i = t; i < EPB; i += 256) {
            int k = k0 + i;
            if (k < Etot) {
                int d = k < E ? dst[k] : k - E;
                atomicAdd(&h[d >> 8], 1);
            }
        }
        __syncthreads();
        pbh[b * 256 + t] = h[t];
        if (h[t]) atomicAdd(bcnt + t, h[t]);
        return;
    }
    b -= nb_bucket;
    if (b < nb_convx) {                       // ---- x fp32 -> bf16 (float4) ----
        int i = b * 256 + t;
        if (i < nx4) {
            float4 v = ((const float4*)x)[i];
            ushort4 u;
            u.x = f2bf(v.x); u.y = f2bf(v.y); u.z = f2bf(v.z); u.w = f2bf(v.w);
            ((ushort4*)X16)[i] = u;
        }
        return;
    }
    b -= nb_convx;
    if (b < 128) {                            // ---- W1 [128][256] -> Wt1 [256][128]
        int id = b * 256 + t;
        int k = id >> 8, m = id & 255;
        Wt1[m * 128 + k] = f2bf(W1[id]);
        return;
    }
    b -= 128;
    if (b < 128) {                            // ---- W2 [256][128] -> Wt2 [128][256]
        int id = b * 256 + t;
        int k = id >> 7, m = id & 127;
        Wt2[m * 256 + k] = f2bf(W2[id]);
        return;
    }
    b -= 128;
    int wave = t >> 6, lane = t & 63;
    if (b < 32) {                             // ---- Q1 [128 k][8] -> pk panels ----
        int k = b * 4 + wave;
        if (k < 128) {
            float p[8];
            #pragma unroll
            for (int h = 0; h < 4; ++h) {
                float w = W1[k * 256 + h * 64 + lane];
                p[h] = w * as1[h * 64 + lane];
                p[4 + h] = w * ad1[h * 64 + lane];
            }
            #pragma unroll
            for (int j = 0; j < 8; ++j)
                #pragma unroll
                for (int o = 32; o; o >>= 1) p[j] += __shfl_xor(p[j], o);
            if (lane == 0) {
                #pragma unroll
                for (int j = 0; j < 8; ++j) {
                    unsigned short hi = f2bf(p[j]);
                    Q1pkhi[j * 128 + k] = hi;
                    Q1pklo[j * 128 + k] = f2bf(p[j] - bf2f(hi));
                }
            }
        }
        return;
    }
    b -= 32;
    {                                         // ---- Q2 [256 k][2] -> pk panels ----
        int k = b * 4 + wave;
        if (k < 256) {
            float w0 = W2[k * 128 + lane], w1 = W2[k * 128 + 64 + lane];
            float s = w0 * as2[lane] + w1 * as2[64 + lane];
            float d = w0 * ad2[lane] + w1 * ad2[64 + lane];
            #pragma unroll
            for (int o = 32; o; o >>= 1) { s += __shfl_xor(s, o); d += __shfl_xor(d, o); }
            if (lane == 0) {
                unsigned short sh = f2bf(s), dh = f2bf(d);
                Q2pkhi[k] = sh;
                Q2pkhi[256 + k] = dh;
                Q2pklo[k] = f2bf(s - bf2f(sh));
                Q2pklo[256 + k] = f2bf(d - bf2f(dh));
            }
        }
    }
}

// ===================== fused: partition + attn1 (X.Q1 via MFMA) ==============
// Partition blocks: bucket base via local LDS scan of bcnt (bscan folded in);
// per-block histogram loaded from pbh (computed by prep -- no re-count pass).
// attn blocks: 64 nodes each, wave = 16 nodes. es/ed = X * (Q1hi + Q1lo).
__global__ __launch_bounds__(256) void part_attn1(const unsigned short* __restrict__ Xb,
                                                  const unsigned short* __restrict__ Q1pkhi,
                                                  const unsigned short* __restrict__ Q1pklo,
                                                  float* __restrict__ es,
                                                  float* __restrict__ ed,
                                                  int N, int PB,
                                                  const int* __restrict__ src,
                                                  const int* __restrict__ dst,
                                                  int E, int Etot,
                                                  const int* __restrict__ bcnt,
                                                  const int* __restrict__ pbh,
                                                  int* __restrict__ bcursor,
                                                  int* __restrict__ ebuf) {
    int t = threadIdx.x;
    if ((int)blockIdx.x < PB) {
        __shared__ int gb[256], lc[256], sc[256];
        int v0 = bcnt[t];
        sc[t] = v0;
        __syncthreads();
        #pragma unroll
        for (int o = 1; o < 256; o <<= 1) {
            int add = t >= o ? sc[t - o] : 0;
            __syncthreads();
            sc[t] += add;
            __syncthreads();
        }
        int mybase = sc[t] - v0;              // exclusive bucket base
        int hv = pbh[(int)blockIdx.x * 256 + t];
        if (hv) gb[t] = mybase + atomicAdd(bcursor + t, hv);
        lc[t] = 0;
        __syncthreads();
        int k0 = (int)blockIdx.x * EPB;
        for (int i = t; i < EPB; i += 256) {
            int k = k0 + i;
            if (k < Etot) {
                int s = k < E ? src[k] : k - E;
                int d = k < E ? dst[k] : k - E;
                int bkt = d >> 8;
                int p = atomicAdd(&lc[bkt], 1);
                ebuf[gb[bkt] + p] = s | ((d & 0xFF) << 16);  // src:16|dlow:8
            }
        }
        return;
    }
    int wave = t >> 6, lane = t & 63;
    int l15 = lane & 15, quad = lane >> 4;
    int n0 = ((int)blockIdx.x - PB) * 64 + wave * 16;
    if (n0 >= N) return;
    int ar = n0 + l15; if (ar >= N) ar = N - 1;
    const unsigned short* arow = Xb + (size_t)ar * 128 + quad * 8;
    const unsigned short* bh = Q1pkhi + l15 * 128 + quad * 8;
    const unsigned short* bl = Q1pklo + l15 * 128 + quad * 8;
    f32x4 acc = {};
    #pragma unroll
    for (int k0 = 0; k0 < 128; k0 += 32) {
        bf16x8 a = *(const bf16x8*)(arow + k0);
        acc = __builtin_amdgcn_mfma_f32_16x16x32_bf16(
            a, *(const bf16x8*)(bh + k0), acc, 0, 0, 0);
        acc = __builtin_amdgcn_mfma_f32_16x16x32_bf16(
            a, *(const bf16x8*)(bl + k0), acc, 0, 0, 0);
    }
    #pragma unroll
    for (int r = 0; r < 4; ++r) {
        int n = n0 + quad * 4 + r;
        if (n < N) {
            if (l15 < 4)      es[n * 4 + l15] = acc[r];
            else if (l15 < 8) ed[n * 4 + (l15 - 4)] = acc[r];
        }
    }
}

// ===================== per-bucket CSR build (XCD-local writes) =================
// Bucket base via local LDS scan of bcnt; also sets rowptr[N] = Etot.
__global__ __launch_bounds__(256) void bucket_scatter(const int* __restrict__ bcnt,
                                                      const int* __restrict__ ebuf,
                                                      int* __restrict__ rowptr,
                                                      int* __restrict__ col,
                                                      int N, int Etot) {
    __shared__ int sb[256], ldeg[256], loff[256], lcur[256];
    int b = blockIdx.x, t = threadIdx.x;
    sb[t] = bcnt[t];
    ldeg[t] = 0;
    __syncthreads();
    #pragma unroll
    for (int o = 1; o < 256; o <<= 1) {
        int add = t >= o ? sb[t - o] : 0;
        __syncthreads();
        sb[t] += add;
        __syncthreads();
    }
    int cnt = bcnt[b];
    int base = sb[b] - cnt;                   // exclusive bucket base
    if (b == 0 && t == 0) rowptr[N] = Etot;
    for (int i = t; i < cnt; i += 256) {
        int e = ebuf[base + i];
        atomicAdd(&ldeg[(e >> 16) & 0xFF], 1);
    }
    __syncthreads();
    int v = ldeg[t];
    loff[t] = v;
    __syncthreads();
    #pragma unroll
    for (int o = 1; o < 256; o <<= 1) {
        int add = t >= o ? loff[t - o] : 0;
        __syncthreads();
        loff[t] += add;
        __syncthreads();
    }
    int excl = loff[t] - v;
    __syncthreads();
    loff[t] = excl;
    lcur[t] = 0;
    int node = b * 256 + t;
    if (node < N) rowptr[node] = base + excl;
    __syncthreads();
    for (int i = t; i < cnt; i += 256) {
        int e = ebuf[base + i];
        int dl = (e >> 16) & 0xFF;
        int p = atomicAdd(&lcur[dl], 1);
        col[base + loff[dl] + p] = e & 0xFFFF;
    }
}

// ===================== agg_l1x: no-max softmax + x-row aggregation ==========
// R4-proven config (fastest of 8 measured variants: ~47 us). Half-wave
// ushort4 gathers, wave-per-node in small independent blocks (TLP + tail
// decoupling are essential: fused variants R10/R12 both collapsed to
// ~1.0 TB/s). At the random-gather memory ceiling (~3.3 TB/s effective).
__global__ __launch_bounds__(256) void agg_l1x(const int* __restrict__ rowptr,
                                               const int* __restrict__ col,
                                               const unsigned short* __restrict__ x16,
                                               const float* __restrict__ es,
                                               const float* __restrict__ ed,
                                               unsigned short* __restrict__ G16,
                                               int N) {
    __shared__ float pl[4][DEG_CAP * 4];
    __shared__ int ic[4][DEG_CAP];
    __shared__ float zs[4][4];
    int wave = threadIdx.x >> 6, lane = threadIdx.x & 63;
    int n = blockIdx.x * 4 + wave;
    if (n >= N) return;
    int h = lane >> 4, l16 = lane & 15;
    int half = lane >> 5, l32 = lane & 31;
    int beg = rowptr[n], end = rowptr[n + 1], deg = end - beg;
    float* myp = pl[wave];
    int* myc = ic[wave];
    f32x4 acc[4] = {};                        // acc[head] = 4 channels at l32*4
    const unsigned short* xb = x16 + l32 * 4;
    if (deg <= DEG_CAP) {
        // phase 1: gather cols + logits + denom (no-max: logits O(+-5), fp32 safe)
        float edv = ed[n * 4 + h];
        float z = 0.f;
        for (int i = l16; i < deg; i += 16) {
            int s = col[beg + i];
            if (h == 0) myc[i] = s;
            float e = es[s * 4 + h] + edv;
            e = e > 0.f ? e : 0.2f * e;
            float pp = __expf(e);
            myp[i * 4 + h] = pp;
            z += pp;
        }
        #pragma unroll
        for (int o = 8; o; o >>= 1) z += __shfl_xor(z, o);
        if (l16 == 0) zs[wave][h] = 1.0f / z;
        __threadfence_block();
        float4 zi = *(float4*)zs[wave];
        int i = 0;
        for (; i + 4 <= deg; i += 4) {
            int iA = i + half, iB = iA + 2;
            int sA = myc[iA], sB = myc[iB];
            float4 pA = *(float4*)(myp + iA * 4);
            float4 pB = *(float4*)(myp + iB * 4);
            ushort4 uA = *(const ushort4*)(xb + (size_t)sA * 128);
            ushort4 uB = *(const ushort4*)(xb + (size_t)sB * 128);
            f32x4 xA = {bf2f(uA.x), bf2f(uA.y), bf2f(uA.z), bf2f(uA.w)};
            acc[0] = fma4(pA.x * zi.x, xA, acc[0]);
            acc[1] = fma4(pA.y * zi.y, xA, acc[1]);
            acc[2] = fma4(pA.z * zi.z, xA, acc[2]);
            acc[3] = fma4(pA.w * zi.w, xA, acc[3]);
            f32x4 xB = {bf2f(uB.x), bf2f(uB.y), bf2f(uB.z), bf2f(uB.w)};
            acc[0] = fma4(pB.x * zi.x, xB, acc[0]);
            acc[1] = fma4(pB.y * zi.y, xB, acc[1]);
            acc[2] = fma4(pB.z * zi.z, xB, acc[2]);
            acc[3] = fma4(pB.w * zi.w, xB, acc[3]);
        }
        for (; i < deg; i += 2) {
            int ii = i + half;
            if (ii < deg) {
                int s = myc[ii];
                float4 p = *(float4*)(myp + ii * 4);
                ushort4 u = *(const ushort4*)(xb + (size_t)s * 128);
                f32x4 xv = {bf2f(u.x), bf2f(u.y), bf2f(u.z), bf2f(u.w)};
                acc[0] = fma4(p.x * zi.x, xv, acc[0]);
                acc[1] = fma4(p.y * zi.y, xv, acc[1]);
                acc[2] = fma4(p.z * zi.z, xv, acc[2]);
                acc[3] = fma4(p.w * zi.w, xv, acc[3]);
            }
        }
    } else {
        // fallback: recompute logits per edge (deg > DEG_CAP, rare)
        float edv = ed[n * 4 + h];
        float z2 = 0.f;
        for (int e = beg + l16; e < end; e += 16) {
            float ev = es[col[e] * 4 + h] + edv;
            ev = ev > 0.f ? ev : 0.2f * ev;
            z2 += __expf(ev);
        }
        #pragma unroll
        for (int o = 8; o; o >>= 1) z2 += __shfl_xor(z2, o);
        if (l16 == 0) zs[wave][h] = 1.0f / z2;
        __threadfence_block();
        float4 zi = *(float4*)zs[wave];
        float4 ed4 = *(const float4*)(ed + n * 4);
        for (int e = beg; e < end; e += 2) {
            int ee = e + half;
            if (ee < end) {
                int s = col[ee];
                float4 es4 = *(const float4*)(es + (size_t)s * 4);
                float e0 = es4.x + ed4.x; e0 = e0 > 0.f ? e0 : 0.2f * e0;
                float e1 = es4.y + ed4.y; e1 = e1 > 0.f ? e1 : 0.2f * e1;
                float e2 = es4.z + ed4.z; e2 = e2 > 0.f ? e2 : 0.2f * e2;
                float e3 = es4.w + ed4.w; e3 = e3 > 0.f ? e3 : 0.2f * e3;
                ushort4 u = *(const ushort4*)(xb + (size_t)s * 128);
                f32x4 xv = {bf2f(u.x), bf2f(u.y), bf2f(u.z), bf2f(u.w)};
                acc[0] = fma4(__expf(e0) * zi.x, xv, acc[0]);
                acc[1] = fma4(__expf(e1) * zi.y, xv, acc[1]);
                acc[2] = fma4(__expf(e2) * zi.z, xv, acc[2]);
                acc[3] = fma4(__expf(e3) * zi.w, xv, acc[3]);
            }
        }
    }
    #pragma unroll
    for (int hh = 0; hh < 4; ++hh)
        #pragma unroll
        for (int c = 0; c < 4; ++c)
            acc[hh][c] += __shfl_xor(acc[hh][c], 32);
    if (half == 0) {
        unsigned short* g = G16 + (size_t)n * 512 + l32 * 4;
        #pragma unroll
        for (int hh = 0; hh < 4; ++hh) {
            ushort4 o = {f2bf(acc[hh][0]), f2bf(acc[hh][1]),
                         f2bf(acc[hh][2]), f2bf(acc[hh][3])};
            *(ushort4*)(g + hh * 128) = o;
        }
    }
}

// ===================== proj2: h1 proj (LDS) + GEMM2 + attn2 fused ===========
// Block = 32 nodes (R6: 1563 blocks lifts resident occupancy vs 782).
__global__ __launch_bounds__(256) void proj2(const unsigned short* __restrict__ G16,
                                             const unsigned short* __restrict__ Wt1,
                                             const float* __restrict__ b1,
                                             const unsigned short* __restrict__ Wt2,
                                             const unsigned short* __restrict__ Q2pkhi,
                                             const unsigned short* __restrict__ Q2pklo,
                                             unsigned short* __restrict__ H2,
                                             float* __restrict__ es,
                                             float* __restrict__ ed, int N) {
    __shared__ unsigned short Hlds[32][264];  // +8 pad; 528B rows (16B aligned)
    int wave = threadIdx.x >> 6, lane = threadIdx.x & 63;
    int l15 = lane & 15, quad = lane >> 4;
    int m0 = blockIdx.x * 32;
    // ---- phase A: per-head projection (32 rows x 64 cols, K=128) into LDS ----
    {
        int h = wave;
        f32x4 acc[2][4] = {};
        int ar[2];
        #pragma unroll
        for (int m = 0; m < 2; ++m) {
            int r = m0 + m * 16 + l15;
            ar[m] = r < N ? r : N - 1;
        }
        const unsigned short* brow = Wt1 + (size_t)(h * 64 + l15) * 128 + quad * 8;
        #pragma unroll
        for (int k0 = 0; k0 < 128; k0 += 32) {
            bf16x8 a[2], b[4];
            #pragma unroll
            for (int m = 0; m < 2; ++m)
                a[m] = *(const bf16x8*)(G16 + (size_t)ar[m] * 512 + h * 128 + quad * 8 + k0);
            #pragma unroll
            for (int nt = 0; nt < 4; ++nt)
                b[nt] = *(const bf16x8*)(brow + (size_t)nt * 16 * 128 + k0);
            #pragma unroll
            for (int m = 0; m < 2; ++m)
                #pragma unroll
                for (int nt = 0; nt < 4; ++nt)
                    acc[m][nt] = __builtin_amdgcn_mfma_f32_16x16x32_bf16(
                        a[m], b[nt], acc[m][nt], 0, 0, 0);
        }
        #pragma unroll
        for (int nt = 0; nt < 4; ++nt) {
            float bias = b1[h * 64 + nt * 16 + l15];
            #pragma unroll
            for (int m = 0; m < 2; ++m)
                #pragma unroll
                for (int r = 0; r < 4; ++r) {
                    float v = acc[m][nt][r] + bias;
                    v = v > 0.f ? v : (__expf(v) - 1.0f);
                    Hlds[m * 16 + quad * 4 + r][h * 64 + nt * 16 + l15] = f2bf(v);
                }
        }
    }
    __syncthreads();
    // ---- phase B1: GEMM2 (32x128 out, K=256); wave covers cols wave*32.. ----
    {
        f32x4 acc2[2][2] = {};
        #pragma unroll
        for (int k0 = 0; k0 < 256; k0 += 32) {
            bf16x8 a[2], b[2];
            #pragma unroll
            for (int m = 0; m < 2; ++m)
                a[m] = *(const bf16x8*)(&Hlds[m * 16 + l15][quad * 8 + k0]);
            #pragma unroll
            for (int j = 0; j < 2; ++j)
                b[j] = *(const bf16x8*)(Wt2 +
                        (size_t)(wave * 32 + j * 16 + l15) * 256 + quad * 8 + k0);
            #pragma unroll
            for (int m = 0; m < 2; ++m)
                #pragma unroll
                for (int j = 0; j < 2; ++j)
                    acc2[m][j] = __builtin_amdgcn_mfma_f32_16x16x32_bf16(
                        a[m], b[j], acc2[m][j], 0, 0, 0);
        }
        #pragma unroll
        for (int m = 0; m < 2; ++m)
            #pragma unroll
            for (int j = 0; j < 2; ++j)
                #pragma unroll
                for (int r = 0; r < 4; ++r) {
                    int row = m0 + m * 16 + quad * 4 + r;
                    if (row < N)
                        H2[(size_t)row * 128 + wave * 32 + j * 16 + l15] =
                            f2bf(acc2[m][j][r]);
                }
    }
    // ---- phase B2: attn2 via MFMA; waves 0-1 cover 16 rows each ----
    if (wave < 2) {
        f32x4 acc = {};
        const unsigned short* bh = Q2pkhi + l15 * 256 + quad * 8;
        const unsigned short* bl = Q2pklo + l15 * 256 + quad * 8;
        #pragma unroll
        for (int k0 = 0; k0 < 256; k0 += 32) {
            bf16x8 a = *(const bf16x8*)(&Hlds[wave * 16 + l15][quad * 8 + k0]);
            acc = __builtin_amdgcn_mfma_f32_16x16x32_bf16(
                a, *(const bf16x8*)(bh + k0), acc, 0, 0, 0);
            acc = __builtin_amdgcn_mfma_f32_16x16x32_bf16(
                a, *(const bf16x8*)(bl + k0), acc, 0, 0, 0);
        }
        #pragma unroll
        for (int r = 0; r < 4; ++r) {
            int n = m0 + wave * 16 + quad * 4 + r;
            if (n < N) {
                if (l15 == 0)      es[n] = acc[r];
                else if (l15 == 1) ed[n] = acc[r];
            }
        }
    }
}

// ===================== agg_l2 (no-max softmax; gather h2 rows 256B) =========
__global__ __launch_bounds__(256) void agg_l2(const int* __restrict__ rowptr,
                                              const int* __restrict__ col,
                                              const unsigned short* __restrict__ h16,
                                              const float* __restrict__ es,
                                              const float* __restrict__ ed,
                                              const float* __restrict__ b2,
                                              float* __restrict__ out, int N) {
    __shared__ float pl[4][DEG_CAP];
    __shared__ int ic[4][DEG_CAP];
    int wave = threadIdx.x >> 6, lane = threadIdx.x & 63;
    int n = blockIdx.x * 4 + wave;
    if (n >= N) return;
    int beg = rowptr[n], end = rowptr[n + 1], deg = end - beg;
    float edv = ed[n];
    float* myp = pl[wave];
    int* myc = ic[wave];
    float z = 0.f, zinv;
    int half = lane >> 5, l32 = lane & 31;
    float4 acc0 = make_float4(0.f, 0.f, 0.f, 0.f);
    float4 acc1 = make_float4(0.f, 0.f, 0.f, 0.f);
    float4 acc2 = make_float4(0.f, 0.f, 0.f, 0.f);
    float4 acc3 = make_float4(0.f, 0.f, 0.f, 0.f);
    if (deg <= DEG_CAP) {
        for (int i = lane; i < deg; i += 64) {
            int s = col[beg + i];
            myc[i] = s;
            float e = es[s] + edv;
            e = e > 0.f ? e : 0.2f * e;
            float pp = __expf(e);
            myp[i] = pp;
            z += pp;
        }
        #pragma unroll
        for (int o = 32; o; o >>= 1) z += __shfl_xor(z, o);
        zinv = 1.0f / z;
        __threadfence_block();
        int i = 0;
        for (; i + 8 <= deg; i += 8) {
            int ii0 = i + half, ii1 = i + 2 + half, ii2 = i + 4 + half, ii3 = i + 6 + half;
            float a0 = myp[ii0] * zinv, a1 = myp[ii1] * zinv;
            float a2 = myp[ii2] * zinv, a3 = myp[ii3] * zinv;
            ushort4 u0 = *(const ushort4*)(h16 + (size_t)myc[ii0] * 128 + l32 * 4);
            ushort4 u1 = *(const ushort4*)(h16 + (size_t)myc[ii1] * 128 + l32 * 4);
            ushort4 u2 = *(const ushort4*)(h16 + (size_t)myc[ii2] * 128 + l32 * 4);
            ushort4 u3 = *(const ushort4*)(h16 + (size_t)myc[ii3] * 128 + l32 * 4);
            acc0.x = fmaf(a0, bf2f(u0.x), acc0.x);
            acc0.y = fmaf(a0, bf2f(u0.y), acc0.y);
            acc0.z = fmaf(a0, bf2f(u0.z), acc0.z);
            acc0.w = fmaf(a0, bf2f(u0.w), acc0.w);
            acc1.x = fmaf(a1, bf2f(u1.x), acc1.x);
            acc1.y = fmaf(a1, bf2f(u1.y), acc1.y);
            acc1.z = fmaf(a1, bf2f(u1.z), acc1.z);
            acc1.w = fmaf(a1, bf2f(u1.w), acc1.w);
            acc2.x = fmaf(a2, bf2f(u2.x), acc2.x);
            acc2.y = fmaf(a2, bf2f(u2.y), acc2.y);
            acc2.z = fmaf(a2, bf2f(u2.z), acc2.z);
            acc2.w = fmaf(a2, bf2f(u2.w), acc2.w);
            acc3.x = fmaf(a3, bf2f(u3.x), acc3.x);
            acc3.y = fmaf(a3, bf2f(u3.y), acc3.y);
            acc3.z = fmaf(a3, bf2f(u3.z), acc3.z);
            acc3.w = fmaf(a3, bf2f(u3.w), acc3.w);
        }
        for (; i < deg; i += 2) {
            int ii = i + half;
            if (ii < deg) {
                float a0 = myp[ii] * zinv;
                ushort4 u0 = *(const ushort4*)(h16 + (size_t)myc[ii] * 128 + l32 * 4);
                acc0.x = fmaf(a0, bf2f(u0.x), acc0.x);
                acc0.y = fmaf(a0, bf2f(u0.y), acc0.y);
                acc0.z = fmaf(a0, bf2f(u0.z), acc0.z);
                acc0.w = fmaf(a0, bf2f(u0.w), acc0.w);
            }
        }
    } else {
        for (int e = beg + lane; e < end; e += 64) {
            float ev = es[col[e]] + edv;
            ev = ev > 0.f ? ev : 0.2f * ev;
            z += __expf(ev);
        }
        #pragma unroll
        for (int o = 32; o; o >>= 1) z += __shfl_xor(z, o);
        zinv = 1.0f / z;
        for (int e = beg; e < end; e += 2) {
            int ee = e + half;
            if (ee < end) {
                int s = col[ee];
                float ev = es[s] + edv;
                ev = ev > 0.f ? ev : 0.2f * ev;
                float alpha = __expf(ev) * zinv;
                ushort4 u = *(const ushort4*)(h16 + (size_t)s * 128 + l32 * 4);
                acc0.x = fmaf(alpha, bf2f(u.x), acc0.x);
                acc0.y = fmaf(alpha, bf2f(u.y), acc0.y);
                acc0.z = fmaf(alpha, bf2f(u.z), acc0.z);
                acc0.w = fmaf(alpha, bf2f(u.w), acc0.w);
            }
        }
    }
    float4 acc = make_float4((acc0.x + acc1.x) + (acc2.x + acc3.x),
                             (acc0.y + acc1.y) + (acc2.y + acc3.y),
                             (acc0.z + acc1.z) + (acc2.z + acc3.z),
                             (acc0.w + acc1.w) + (acc2.w + acc3.w));
    acc.x += __shfl_xor(acc.x, 32);
    acc.y += __shfl_xor(acc.y, 32);
    acc.z += __shfl_xor(acc.z, 32);
    acc.w += __shfl_xor(acc.w, 32);
    if (half == 0) {
        float4 bv = *(const float4*)(b2 + l32 * 4);
        *(float4*)(out + (size_t)n * 128 + l32 * 4) =
            make_float4(acc.x + bv.x, acc.y + bv.y, acc.z + bv.z, acc.w + bv.w);
    }
}

// ===================== launch =====================
extern "C" void kernel_launch(void* const* d_in, const int* in_sizes, int n_in,
                              void* d_out, int out_size, void* d_ws, size_t ws_size,
                              hipStream_t stream) {
    const float* x   = (const float*)d_in[0];
    const int*   ei  = (const int*)d_in[1];
    const float* W1  = (const float*)d_in[2];
    const float* as1 = (const float*)d_in[3];
    const float* ad1 = (const float*)d_in[4];
    const float* b1  = (const float*)d_in[5];
    const float* W2  = (const float*)d_in[6];
    const float* as2 = (const float*)d_in[7];
    const float* ad2 = (const float*)d_in[8];
    const float* b2  = (const float*)d_in[9];
    float* out = (float*)d_out;

    const int N = in_sizes[0] / 128;   // 50000
    const int E = in_sizes[1] / 2;     // 800000
    const int Etot = E + N;
    const int* src = ei;
    const int* dst = ei + E;
    const int NBUCK = (N + 255) / 256;        // 196 buckets of 256 nodes
    const int PB = (Etot + EPB - 1) / EPB;    // fat partition blocks

    // ---- workspace layout (16B-aligned chunks) ----
    char* p = (char*)d_ws;
    unsigned short* X16 = (unsigned short*)p; p += (size_t)N * 128 * 2;
    unsigned short* H2  = (unsigned short*)p; p += (size_t)N * 128 * 2;
    unsigned short* G16 = (unsigned short*)p; p += (size_t)N * 512 * 2;
    unsigned short* Wt1 = (unsigned short*)p; p += (size_t)256 * 128 * 2;
    unsigned short* Wt2 = (unsigned short*)p; p += (size_t)128 * 256 * 2;
    unsigned short* Q1pkhi = (unsigned short*)p; p += 16 * 128 * 2;
    unsigned short* Q1pklo = (unsigned short*)p; p += 16 * 128 * 2;
    unsigned short* Q2pkhi = (unsigned short*)p; p += 16 * 256 * 2;
    unsigned short* Q2pklo = (unsigned short*)p; p += 16 * 256 * 2;
    float* es1 = (float*)p;               p += (size_t)N * 4 * 4;
    float* ed1 = (float*)p;               p += (size_t)N * 4 * 4;
    float* es2 = (float*)p;               p += (size_t)N * 4;
    float* ed2 = (float*)p;               p += (size_t)N * 4;
    int* bcnt = (int*)p;                  p += 256 * 4;   // memset to 0 (with bcursor)
    int* bcursor = (int*)p;               p += 256 * 4;
    int* pbh = (int*)p;                   p += (size_t)PB * 256 * 4;
    int* ebuf = (int*)p;                  p += (size_t)Etot * 4;
    int* col = (int*)p;                   p += (size_t)Etot * 4;
    int* rowptr = (int*)p;                p += (size_t)(N + 1) * 4;

    // ---- prep (bucket-count first, then conv + Wt + Qpk) ----
    const int nx4 = N * 128 / 4;
    const int nb_convx = (nx4 + 255) / 256;
    const int nb_prep = PB + nb_convx + 128 + 128 + 32 + 64;
    hipMemsetAsync(bcnt, 0, 512 * sizeof(int), stream);   // bcnt + bcursor
    prep<<<nb_prep, 256, 0, stream>>>(x, X16, nx4, dst, E, Etot, bcnt, pbh,
                                      W1, Wt1, W2, Wt2, as1, ad1, Q1pkhi, Q1pklo,
                                      as2, ad2, Q2pkhi, Q2pklo, PB, nb_convx);

    // ---- partition + attn1 (MFMA, 64 nodes/block); scan + pbh reuse ----
    const int AB = (N + 63) / 64;
    part_attn1<<<PB + AB, 256, 0, stream>>>(X16, Q1pkhi, Q1pklo, es1, ed1, N, PB,
                                            src, dst, E, Etot, bcnt, pbh,
                                            bcursor, ebuf);

    // ---- per-bucket CSR build (XCD-local writes); scan folded in ----
    bucket_scatter<<<NBUCK, 256, 0, stream>>>(bcnt, ebuf, rowptr, col, N, Etot);

    // ---- layer 1 aggregation (wave per node, ushort4 half-wave gather) ----
    agg_l1x<<<(N + 3) / 4, 256, 0, stream>>>(rowptr, col, X16, es1, ed1, G16, N);

    // ---- fused: h1 projection + GEMM2 + attn2 (32-node tiles) ----
    const int tiles = (N + 31) / 32;
    proj2<<<tiles, 256, 0, stream>>>(G16, Wt1, b1, Wt2, Q2pkhi, Q2pklo,
                                     H2, es2, ed2, N);

    // ---- layer 2 aggregation ----
    agg_l2<<<(N + 3) / 4, 256, 0, stream>>>(rowptr, col, H2, es2, ed2, b2, out, N);
}